// Round 1
// baseline (586.640 us; speedup 1.0000x reference)
//
#include <hip/hip_runtime.h>
#include <math.h>

#define DIM 128
#define NEG_K 20

// Numerically stable log(sigmoid(x)) = min(x,0) - log1p(exp(-|x|))
__device__ __forceinline__ float log_sigmoid(float x) {
    float m = fminf(x, 0.0f);
    return m - log1pf(__expf(-fabsf(x)));
}

// One half-wave (32 lanes) per batch element. Each lane holds float4 -> 32*16B
// = 512B = one full embedding row per vector load (coalesced: rows are
// contiguous even though row indices are random).
__global__ __launch_bounds__(256) void sgns_loss_kernel(
    const int* __restrict__ target,
    const int* __restrict__ context,
    const int* __restrict__ neg,
    const float* __restrict__ emb,
    float* __restrict__ out,
    int B)
{
    const int tid  = blockIdx.x * blockDim.x + threadIdx.x;
    const int lane = threadIdx.x & 63;
    const int sub  = lane & 31;                 // lane within half-wave
    const int hw   = tid >> 5;                  // global half-wave id
    const int nHW  = (gridDim.x * blockDim.x) >> 5;

    float local = 0.0f;
    for (int b = hw; b < B; b += nHW) {
        const float4 v = *(const float4*)(emb + (size_t)target[b]  * DIM + sub * 4);
        const float4 u = *(const float4*)(emb + (size_t)context[b] * DIM + sub * 4);

        // sum_k dot(u_hat_k, v) == dot(sum_k u_hat_k, v): accumulate rows first.
        float4 ns = make_float4(0.f, 0.f, 0.f, 0.f);
        const int* __restrict__ nb = neg + (size_t)b * NEG_K;
        #pragma unroll
        for (int k = 0; k < NEG_K; ++k) {
            const float4 un = *(const float4*)(emb + (size_t)nb[k] * DIM + sub * 4);
            ns.x += un.x; ns.y += un.y; ns.z += un.z; ns.w += un.w;
        }

        float pos = u.x * v.x + u.y * v.y + u.z * v.z + u.w * v.w;
        float ng  = ns.x * v.x + ns.y * v.y + ns.z * v.z + ns.w * v.w;

        // Reduce over the 32 lanes of this half-wave (xor<32 never crosses halves).
        #pragma unroll
        for (int off = 16; off; off >>= 1) {
            pos += __shfl_xor(pos, off);
            ng  += __shfl_xor(ng,  off);
        }
        if (sub == 0) local += log_sigmoid(pos) + log_sigmoid(-ng);
    }

    // Full-wave reduction (now crossing halves is fine), then block, then atomic.
    #pragma unroll
    for (int off = 32; off; off >>= 1) local += __shfl_xor(local, off);

    __shared__ float wsum[4];
    const int w = threadIdx.x >> 6;
    if (lane == 0) wsum[w] = local;
    __syncthreads();
    if (threadIdx.x == 0) {
        float s = wsum[0] + wsum[1] + wsum[2] + wsum[3];
        atomicAdd(out, -s / (float)B);
    }
}

extern "C" void kernel_launch(void* const* d_in, const int* in_sizes, int n_in,
                              void* d_out, int out_size, void* d_ws, size_t ws_size,
                              hipStream_t stream) {
    const int*   target  = (const int*)d_in[0];
    const int*   context = (const int*)d_in[1];
    const int*   neg     = (const int*)d_in[2];
    const float* emb     = (const float*)d_in[3];
    float* out = (float*)d_out;
    const int B = in_sizes[0];

    hipMemsetAsync(out, 0, sizeof(float), stream);

    // One half-wave per batch element: B*32 threads.
    const int threads = 256;
    const int blocks  = (B * 32 + threads - 1) / threads;
    sgns_loss_kernel<<<blocks, threads, 0, stream>>>(target, context, neg, emb, out, B);
}

// Round 2
// 583.480 us; speedup vs baseline: 1.0054x; 1.0054x over previous
//
#include <hip/hip_runtime.h>
#include <math.h>

#define DIM 128
#define NEG_K 20

// Numerically stable log(sigmoid(x)) = min(x,0) - log1p(exp(-|x|))
__device__ __forceinline__ float log_sigmoid(float x) {
    float m = fminf(x, 0.0f);
    return m - log1pf(__expf(-fabsf(x)));
}

// One half-wave (32 lanes) per batch element; lane holds float4 -> 32*16B =
// 512B = one full embedding row per vectorized gather (coalesced within row).
// Per-block partial sums go to ws; NO global atomics (2048 same-address
// device-scope atomicAdds serialize across XCDs).
__global__ __launch_bounds__(256) void sgns_partial_kernel(
    const int* __restrict__ target,
    const int* __restrict__ context,
    const int* __restrict__ neg,
    const float* __restrict__ emb,
    float* __restrict__ partials,
    int B)
{
    const int tid  = blockIdx.x * blockDim.x + threadIdx.x;
    const int lane = threadIdx.x & 63;
    const int sub  = lane & 31;                 // lane within half-wave
    const int hw   = tid >> 5;                  // global half-wave id
    const int nHW  = (gridDim.x * blockDim.x) >> 5;

    float local = 0.0f;
    for (int b = hw; b < B; b += nHW) {
        const int tgt = target[b];
        const int ctx = context[b];
        // neg row = 20 ints = 80B, 80*b is always 16B-aligned -> 5x int4
        const int4* __restrict__ nbv = (const int4*)(neg + (size_t)b * NEG_K);
        const int4 n0 = nbv[0], n1 = nbv[1], n2 = nbv[2], n3 = nbv[3], n4 = nbv[4];

        const float4 v = *(const float4*)(emb + (size_t)tgt * DIM + sub * 4);
        const float4 u = *(const float4*)(emb + (size_t)ctx * DIM + sub * 4);

        // sum_k dot(u_hat_k, v) == dot(sum_k u_hat_k, v): accumulate rows.
        float4 ns = make_float4(0.f, 0.f, 0.f, 0.f);
#define ACC(I) { const float4 un = *(const float4*)(emb + (size_t)(I) * DIM + sub * 4); \
                 ns.x += un.x; ns.y += un.y; ns.z += un.z; ns.w += un.w; }
        ACC(n0.x) ACC(n0.y) ACC(n0.z) ACC(n0.w)
        ACC(n1.x) ACC(n1.y) ACC(n1.z) ACC(n1.w)
        ACC(n2.x) ACC(n2.y) ACC(n2.z) ACC(n2.w)
        ACC(n3.x) ACC(n3.y) ACC(n3.z) ACC(n3.w)
        ACC(n4.x) ACC(n4.y) ACC(n4.z) ACC(n4.w)
#undef ACC

        float pos = u.x * v.x + u.y * v.y + u.z * v.z + u.w * v.w;
        float ng  = ns.x * v.x + ns.y * v.y + ns.z * v.z + ns.w * v.w;

        // Reduce across the 32 lanes of this half-wave (xor<32 stays in half).
        #pragma unroll
        for (int off = 16; off; off >>= 1) {
            pos += __shfl_xor(pos, off);
            ng  += __shfl_xor(ng,  off);
        }
        if (sub == 0) local += log_sigmoid(pos) + log_sigmoid(-ng);
    }

    // Full-wave then block reduction -> one partial per block.
    #pragma unroll
    for (int off = 32; off; off >>= 1) local += __shfl_xor(local, off);

    __shared__ float wsum[4];
    if (lane == 0) wsum[threadIdx.x >> 6] = local;
    __syncthreads();
    if (threadIdx.x == 0)
        partials[blockIdx.x] = wsum[0] + wsum[1] + wsum[2] + wsum[3];
}

// Single-block reduction of the per-block partials; writes the final loss.
__global__ __launch_bounds__(256) void sgns_reduce_kernel(
    const float* __restrict__ partials, float* __restrict__ out,
    int n, float invB)
{
    float s = 0.0f;
    for (int i = threadIdx.x; i < n; i += 256) s += partials[i];
    #pragma unroll
    for (int off = 32; off; off >>= 1) s += __shfl_xor(s, off);

    __shared__ float wsum[4];
    const int lane = threadIdx.x & 63;
    if (lane == 0) wsum[threadIdx.x >> 6] = s;
    __syncthreads();
    if (threadIdx.x == 0)
        out[0] = -(wsum[0] + wsum[1] + wsum[2] + wsum[3]) * invB;
}

extern "C" void kernel_launch(void* const* d_in, const int* in_sizes, int n_in,
                              void* d_out, int out_size, void* d_ws, size_t ws_size,
                              hipStream_t stream) {
    const int*   target  = (const int*)d_in[0];
    const int*   context = (const int*)d_in[1];
    const int*   neg     = (const int*)d_in[2];
    const float* emb     = (const float*)d_in[3];
    float* out      = (float*)d_out;
    float* partials = (float*)d_ws;
    const int B = in_sizes[0];

    const int threads = 256;
    const int blocks  = (B * 32 + threads - 1) / threads;   // one half-wave per b

    sgns_partial_kernel<<<blocks, threads, 0, stream>>>(target, context, neg,
                                                        emb, partials, B);
    sgns_reduce_kernel<<<1, threads, 0, stream>>>(partials, out, blocks,
                                                  1.0f / (float)B);
}